// Round 5
// baseline (271.231 us; speedup 1.0000x reference)
//
#include <hip/hip_runtime.h>
#include <stdint.h>

#define NUM_ENTRIES 1000000
#define NUM_HINTS   32768
#define MAX_SUBSET  512
#define CHUNKS      5

// 16B-vector type with 4B alignment guarantee: entries rows are 20B apart, so
// the dwordx4 load is only dword-aligned (HW-legal on gfx950 global loads).
typedef unsigned uint4a4 __attribute__((ext_vector_type(4), aligned(4)));

// One wave (64 lanes) per hint; lane handles 8 slots (stride 64).
// Confirmed layouts (round 4 passed with detection): entries int32, indices
// int32, mask bytes. Detection retained as a cheap guard (wave-uniform).
// Gather is vectorized: dwordx4 + dword per valid lane (was 5x dword).
// Streams (indices/mask) use nontemporal loads to keep L2 for the entries
// table. Accumulate 32-bit only (XOR commutes with truncation; out is int32).
__global__ __launch_bounds__(256) void hint_xor_kernel(
    const void* __restrict__ entries_v,
    const void* __restrict__ indices_v,
    const void* __restrict__ mask_v,
    int* __restrict__ out)
{
    const int wave = threadIdx.x >> 6;
    const int lane = threadIdx.x & 63;
    const int hint = blockIdx.x * 4 + wave;

    // ---- layout detection (wave-uniform votes, FP <= 2^-64) ----
    const unsigned* ew = (const unsigned*)entries_v;
    const unsigned* iw = (const unsigned*)indices_v;
    const unsigned* mw = (const unsigned*)mask_v;
    const unsigned es = ew[lane];
    const unsigned is = iw[lane];
    const unsigned ms = mw[lane];
    const bool odd = (lane & 1) != 0;

    const bool ent32  = __any(odd && (es & 0xC0000000u));
    const bool idx32  = __any(odd && (is != 0u));
    const bool m_bytes = __any((ms != 0u) && (ms != 1u) && (ms != 0x3f800000u));
    const bool m_odd_nz = __any(odd && (ms != 0u));
    const int  mstep = m_odd_nz ? 1 : 2;

    const int*            idx32p = (const int*)indices_v;
    const long long*      idx64p = (const long long*)indices_v;
    const unsigned char*  m8p    = (const unsigned char*)mask_v;
    const unsigned*       m32p   = (const unsigned*)mask_v;

    const size_t rowoff = (size_t)hint * MAX_SUBSET;

    unsigned a0 = 0, a1 = 0, a2 = 0, a3 = 0, a4 = 0;

    #pragma unroll
    for (int k = 0; k < 8; ++k) {
        const size_t s = rowoff + (size_t)(k * 64 + lane);

        long long idx;
        if (idx32) idx = (long long)__builtin_nontemporal_load(idx32p + s);
        else       idx = __builtin_nontemporal_load(idx64p + s);

        unsigned mv;
        if (m_bytes) mv = (unsigned)__builtin_nontemporal_load(m8p + s);
        else         mv = __builtin_nontemporal_load(m32p + s * (size_t)mstep);

        // bounds guard: misdetection becomes a wrong answer, not a page fault
        const bool v = (mv != 0u) &&
                       ((unsigned long long)idx < (unsigned long long)NUM_ENTRIES);

        if (v) {
            if (ent32) {
                const char* e = (const char*)entries_v + (size_t)idx * 20u;
                const uint4a4 q = *(const uint4a4*)e;            // dwordx4
                const unsigned t = *(const unsigned*)(e + 16);   // dword
                a0 ^= q.x; a1 ^= q.y; a2 ^= q.z; a3 ^= q.w; a4 ^= t;
            } else {
                // int64 entries: XOR only the low dwords (truncation commutes)
                const unsigned* e = (const unsigned*)entries_v + (size_t)idx * 10u;
                a0 ^= e[0]; a1 ^= e[2]; a2 ^= e[4]; a3 ^= e[6]; a4 ^= e[8];
            }
        }
    }

    // 64-lane XOR butterfly (32-bit -> 5 shuffles/step)
    #pragma unroll
    for (int off = 32; off >= 1; off >>= 1) {
        a0 ^= (unsigned)__shfl_xor((int)a0, off, 64);
        a1 ^= (unsigned)__shfl_xor((int)a1, off, 64);
        a2 ^= (unsigned)__shfl_xor((int)a2, off, 64);
        a3 ^= (unsigned)__shfl_xor((int)a3, off, 64);
        a4 ^= (unsigned)__shfl_xor((int)a4, off, 64);
    }

    // coalesced epilogue: lanes 0..4 write one dword each
    if (lane < 5) {
        unsigned r = a0;
        r = (lane == 1) ? a1 : r;
        r = (lane == 2) ? a2 : r;
        r = (lane == 3) ? a3 : r;
        r = (lane == 4) ? a4 : r;
        out[(size_t)hint * CHUNKS + lane] = (int)r;
    }
}

extern "C" void kernel_launch(void* const* d_in, const int* in_sizes, int n_in,
                              void* d_out, int out_size, void* d_ws, size_t ws_size,
                              hipStream_t stream) {
    const void* entries = d_in[0];
    const void* indices = d_in[1];
    const void* mask    = d_in[2];
    int*        out     = (int*)d_out;

    // 4 waves/block, one wave per hint -> 32768/4 = 8192 blocks
    hint_xor_kernel<<<NUM_HINTS / 4, 256, 0, stream>>>(entries, indices, mask, out);
}